// Round 1
// baseline (593.267 us; speedup 1.0000x reference)
//
#include <hip/hip_runtime.h>
#include <hip/hip_bf16.h>
#include <math.h>

#define NEG_INF (-1e9f)
#define B_   16
#define C_   192
#define TX   384
#define TY   1536

#define BM 64
#define BN 64
#define BK 16

// ---------------------------------------------------------------------------
// K1: per-(b,t) row constants r = logp1 + logp4
//   r[b,t] = sum_c (-0.5*log(2pi) - logs) + sum_c (-0.5*m^2*exp(-2*logs))
// ---------------------------------------------------------------------------
__global__ __launch_bounds__(128) void k_rowconst(const float* __restrict__ m_p,
                                                  const float* __restrict__ logs_p,
                                                  float* __restrict__ r) {
    const int b = blockIdx.y;
    const int t = blockIdx.x * 128 + threadIdx.x;
    const float* mp = m_p + b * C_ * TX + t;
    const float* lp = logs_p + b * C_ * TX + t;
    const float c0 = -0.9189385332046727f;  // -0.5*log(2*pi)
    float s = 0.0f;
    for (int c = 0; c < C_; ++c) {
        float ls = lp[c * TX];
        float m  = mp[c * TX];
        float os = expf(-2.0f * ls);
        s += (c0 - ls) - 0.5f * m * m * os;
    }
    r[b * TX + t] = s;
}

// ---------------------------------------------------------------------------
// K2: logp[b,t,s] = r[b,t] + sum_c ( os[c,t]*(-0.5*z[c,s]^2) + (m*os)[c,t]*z[c,s] )
// fp32 tiled GEMM (vector ALU; no fp32 MFMA on CDNA4). 64x64 tile, BK=16,
// 256 threads, 4x4 accum per thread. Output written into d_out as [B,Tx,Ty].
// ---------------------------------------------------------------------------
__global__ __launch_bounds__(256) void k_logp(const float* __restrict__ z_p,
                                              const float* __restrict__ m_p,
                                              const float* __restrict__ logs_p,
                                              const float* __restrict__ r,
                                              float* __restrict__ out) {
    __shared__ float A1s[BK][BM];
    __shared__ float A2s[BK][BM];
    __shared__ float U1s[BK][BN];
    __shared__ float U2s[BK][BN];

    const int b   = blockIdx.z;
    const int tn0 = blockIdx.x * BN;   // s-dim
    const int tm0 = blockIdx.y * BM;   // t-dim
    const int tid = threadIdx.x;
    const int lrow = tid >> 4;           // 0..15 (k row for staging)
    const int lcol = (tid & 15) << 2;    // 0,4,...,60
    const int tx_ = tid & 15;            // n quadrant
    const int ty_ = tid >> 4;            // m quadrant

    const float* mb = m_p + b * C_ * TX;
    const float* lb = logs_p + b * C_ * TX;
    const float* zb = z_p + b * C_ * TY;

    float acc[4][4] = {};

    for (int kk = 0; kk < C_; kk += BK) {
        float4 m4 = *(const float4*)(mb + (kk + lrow) * TX + tm0 + lcol);
        float4 l4 = *(const float4*)(lb + (kk + lrow) * TX + tm0 + lcol);
        float4 z4 = *(const float4*)(zb + (kk + lrow) * TY + tn0 + lcol);

        float osv[4], a2v[4], u1v[4], u2v[4];
        const float mm[4] = {m4.x, m4.y, m4.z, m4.w};
        const float ll[4] = {l4.x, l4.y, l4.z, l4.w};
        const float zz[4] = {z4.x, z4.y, z4.z, z4.w};
#pragma unroll
        for (int i = 0; i < 4; ++i) {
            float os = expf(-2.0f * ll[i]);
            osv[i] = os;
            a2v[i] = mm[i] * os;
            u1v[i] = -0.5f * zz[i] * zz[i];
            u2v[i] = zz[i];
        }

        __syncthreads();   // protect previous iteration's LDS reads
#pragma unroll
        for (int i = 0; i < 4; ++i) {
            A1s[lrow][lcol + i] = osv[i];
            A2s[lrow][lcol + i] = a2v[i];
            U1s[lrow][lcol + i] = u1v[i];
            U2s[lrow][lcol + i] = u2v[i];
        }
        __syncthreads();

#pragma unroll
        for (int k = 0; k < BK; ++k) {
            float4 a1 = *(const float4*)&A1s[k][ty_ * 4];
            float4 a2 = *(const float4*)&A2s[k][ty_ * 4];
            float4 u1 = *(const float4*)&U1s[k][tx_ * 4];
            float4 u2 = *(const float4*)&U2s[k][tx_ * 4];
            const float a1a[4] = {a1.x, a1.y, a1.z, a1.w};
            const float a2a[4] = {a2.x, a2.y, a2.z, a2.w};
            const float u1a[4] = {u1.x, u1.y, u1.z, u1.w};
            const float u2a[4] = {u2.x, u2.y, u2.z, u2.w};
#pragma unroll
            for (int i = 0; i < 4; ++i)
#pragma unroll
                for (int j = 0; j < 4; ++j)
                    acc[i][j] = fmaf(a1a[i], u1a[j], fmaf(a2a[i], u2a[j], acc[i][j]));
        }
    }

#pragma unroll
    for (int i = 0; i < 4; ++i) {
        const int row = tm0 + ty_ * 4 + i;
        const float rr = r[b * TX + row];
        float4 o;
        o.x = acc[i][0] + rr;
        o.y = acc[i][1] + rr;
        o.z = acc[i][2] + rr;
        o.w = acc[i][3] + rr;
        *(float4*)(out + (size_t)(b * TX + row) * TY + tn0 + tx_ * 4) = o;
    }
}

// ---------------------------------------------------------------------------
// K3: monotonic alignment search. One block per batch (384 threads = 6 waves).
// Forward DP over y, recording backtrack decision bits in LDS (72KB), then a
// serial LDS bit-chase produces the idx trajectory.
// ---------------------------------------------------------------------------
__global__ __launch_bounds__(384) void k_dp(const float* __restrict__ logp,
                                            const float* __restrict__ x_mask,
                                            const float* __restrict__ y_mask,
                                            int* __restrict__ idx_out) {
    extern __shared__ unsigned char smem[];
    unsigned long long* decw = (unsigned long long*)smem;        // [TY][6]
    float* vbuf = (float*)(smem + (size_t)TY * 6 * 8);           // [2][TX]
    __shared__ int s_tx, s_ty;

    const int b = blockIdx.x;
    const int x = threadIdx.x;

    if (x == 0) { s_tx = 0; s_ty = 0; }
    __syncthreads();
    {
        int p = x_mask[b * TX + x] > 0.5f;
        unsigned long long msk = __ballot(p);
        if ((x & 63) == 0) atomicAdd(&s_tx, __popcll(msk));
#pragma unroll
        for (int i = 0; i < TY / TX; ++i) {
            int y = x + i * TX;
            p = y_mask[b * TY + y] > 0.5f;
            msk = __ballot(p);
            if ((x & 63) == 0) atomicAdd(&s_ty, __popcll(msk));
        }
    }
    __syncthreads();
    const int tx = s_tx;
    const int ty = s_ty;

    const float* lp = logp + ((size_t)(b * TX + x)) * TY;

    float v = NEG_INF;           // vals[y-1][x]
    float c0 = lp[0];
    float c1 = lp[1];
    int buf = 0;

    for (int y = 0; y < TY; ++y) {
        float c = c0;
        c0 = c1;
        if (y + 2 < TY) c1 = lp[y + 2];

        vbuf[buf * TX + x] = v;
        __syncthreads();
        float vm = (x > 0) ? vbuf[buf * TX + x - 1] : NEG_INF;   // vals[y-1][x-1]

        // backtrack decision bit: uses raw vals[y-1], exactly as reference bwd
        bool dec = (x != 0) && ((x == y) || (v < vm));
        unsigned long long bm = __ballot(dec);
        if ((x & 63) == 0) decw[y * 6 + (x >> 6)] = bm;

        float vs  = (x == y) ? NEG_INF : v;
        float vmv = (x == 0) ? ((y == 0) ? 0.0f : NEG_INF) : vm;
        float nv  = fmaxf(vs, vmv) + c;
        bool feas = (x <= y) && (x >= tx + y - ty);
        v = feas ? nv : NEG_INF;

        buf ^= 1;
    }
    __syncthreads();

    if (x == 0) {
        int idx = tx - 1;
        int* io = idx_out + b * TY;
        for (int y = TY - 1; y >= 0; --y) {
            const bool active = y < ty;
            io[y] = active ? idx : -1;
            if (active) {
                unsigned long long w = decw[y * 6 + (idx >> 6)];
                if ((w >> (idx & 63)) & 1ULL) idx--;
            }
        }
    }
}

// ---------------------------------------------------------------------------
// K4: write the one-hot path. Fully overwrites d_out (which held logp).
// ---------------------------------------------------------------------------
__global__ __launch_bounds__(384) void k_path(const int* __restrict__ idx_arr,
                                              float* __restrict__ out) {
    const int b = blockIdx.y;
    const int x = blockIdx.x;
    const int t = threadIdx.x;       // one float4 per thread along y
    const int y0 = t * 4;
    int4 iv = *(const int4*)(idx_arr + b * TY + y0);
    float4 o;
    o.x = (iv.x == x) ? 1.0f : 0.0f;
    o.y = (iv.y == x) ? 1.0f : 0.0f;
    o.z = (iv.z == x) ? 1.0f : 0.0f;
    o.w = (iv.w == x) ? 1.0f : 0.0f;
    *(float4*)(out + ((size_t)(b * TX + x)) * TY + y0) = o;
}

// ---------------------------------------------------------------------------
extern "C" void kernel_launch(void* const* d_in, const int* in_sizes, int n_in,
                              void* d_out, int out_size, void* d_ws, size_t ws_size,
                              hipStream_t stream) {
    const float* z_p    = (const float*)d_in[0];
    const float* m_p    = (const float*)d_in[1];
    const float* logs_p = (const float*)d_in[2];
    const float* x_mask = (const float*)d_in[3];
    const float* y_mask = (const float*)d_in[4];
    float* out = (float*)d_out;

    float* r       = (float*)d_ws;                           // B*TX floats
    int*   idx_arr = (int*)((char*)d_ws + B_ * TX * 4);      // B*TY ints

    // K3 needs 76800B dynamic LDS (> 64KB default cap)
    static const size_t dp_smem = (size_t)TY * 6 * 8 + 2 * TX * 4;
    (void)hipFuncSetAttribute((const void*)k_dp,
                              hipFuncAttributeMaxDynamicSharedMemorySize,
                              (int)dp_smem);

    k_rowconst<<<dim3(TX / 128, B_), 128, 0, stream>>>(m_p, logs_p, r);
    k_logp<<<dim3(TY / BN, TX / BM, B_), 256, 0, stream>>>(z_p, m_p, logs_p, r, out);
    k_dp<<<B_, TX, dp_smem, stream>>>(out, x_mask, y_mask, idx_arr);
    k_path<<<dim3(TX, B_), TX, 0, stream>>>(idx_arr, out);
}